// Round 5
// baseline (467.560 us; speedup 1.0000x reference)
//
#include <hip/hip_runtime.h>
#include <hip/hip_bf16.h>

#define B 2
#define S 8192
#define H 16
#define D 64
#define NB 32          // S / BS
#define BS 256
#define SAMP 256
#define BH (B*H)
#define BHS (B*H*S)
#define BSHD (B*S*H*D)
#define LOG32 3.4657359027997265f   // log(8192/256)

typedef float f32x4 __attribute__((ext_vector_type(4)));
typedef short bf16x8 __attribute__((ext_vector_type(8)));

__device__ __forceinline__ unsigned short f2bf(float x) {
    unsigned int u = __builtin_bit_cast(unsigned int, x);
    u += 0x7fffu + ((u >> 16) & 1u);       // round-to-nearest-even
    return (unsigned short)(u >> 16);
}
__device__ __forceinline__ unsigned int pack2(float a, float b) {
    return (unsigned int)f2bf(a) | ((unsigned int)f2bf(b) << 16);
}

// ---------------------------------------------------------------------------
// Kernel 1: LSH hash + bf16 pre-conversion (Q*0.125, K, V).
// Block = 256 thr = 16 s x 16 h -> wave footprint is contiguous 16 KB
// (lane stride 256 B).  Per-array loops keep live registers low.
// Hash writes staged via LDS, out as coalesced int4.
// ---------------------------------------------------------------------------
__global__ __launch_bounds__(256) void k_prep(const float* __restrict__ q,
                                              const float* __restrict__ k,
                                              const float* __restrict__ v,
                                              const float* __restrict__ pd,
                                              int* __restrict__ hq,
                                              int* __restrict__ hk,
                                              unsigned short* __restrict__ qbf,
                                              unsigned short* __restrict__ kbf,
                                              unsigned short* __restrict__ vbf) {
    __shared__ float spd[D * 8];
    __shared__ int   ht[2][16][16];   // [q/k][h][s_local]
    const int t = threadIdx.x;
    for (int i = t; i < D * 8; i += 256) spd[i] = pd[i];
    __syncthreads();

    const int b  = blockIdx.x >> 9;        // 512 s-chunks per batch
    const int s0 = (blockIdx.x & 511) * 16;
    const int sl = t >> 4;                 // s_local 0..15
    const int h  = t & 15;
    const int base = ((b * S + s0 + sl) * H + h) << 6;

    // ---- Q: hash dots + scaled bf16 write ----
    {
        float d[8];
#pragma unroll
        for (int p = 0; p < 8; ++p) d[p] = 0.f;
#pragma unroll
        for (int i = 0; i < 8; ++i) {
            float4 x0 = ((const float4*)(q + base + i * 8))[0];
            float4 x1 = ((const float4*)(q + base + i * 8))[1];
#pragma unroll
            for (int p = 0; p < 8; ++p) {
                d[p] += x0.x * spd[(8*i+0)*8+p] + x0.y * spd[(8*i+1)*8+p]
                      + x0.z * spd[(8*i+2)*8+p] + x0.w * spd[(8*i+3)*8+p]
                      + x1.x * spd[(8*i+4)*8+p] + x1.y * spd[(8*i+5)*8+p]
                      + x1.z * spd[(8*i+6)*8+p] + x1.w * spd[(8*i+7)*8+p];
            }
            uint4 u;
            u.x = pack2(x0.x * 0.125f, x0.y * 0.125f);
            u.y = pack2(x0.z * 0.125f, x0.w * 0.125f);
            u.z = pack2(x1.x * 0.125f, x1.y * 0.125f);
            u.w = pack2(x1.z * 0.125f, x1.w * 0.125f);
            *(uint4*)(qbf + base + i * 8) = u;
        }
        int bits = 0;
#pragma unroll
        for (int p = 0; p < 8; ++p) bits |= (d[p] > 0.f) ? (1 << p) : 0;
        ht[0][h][sl] = bits ^ (bits >> 1);
    }
    // ---- K: hash dots + bf16 write ----
    {
        float d[8];
#pragma unroll
        for (int p = 0; p < 8; ++p) d[p] = 0.f;
#pragma unroll
        for (int i = 0; i < 8; ++i) {
            float4 x0 = ((const float4*)(k + base + i * 8))[0];
            float4 x1 = ((const float4*)(k + base + i * 8))[1];
#pragma unroll
            for (int p = 0; p < 8; ++p) {
                d[p] += x0.x * spd[(8*i+0)*8+p] + x0.y * spd[(8*i+1)*8+p]
                      + x0.z * spd[(8*i+2)*8+p] + x0.w * spd[(8*i+3)*8+p]
                      + x1.x * spd[(8*i+4)*8+p] + x1.y * spd[(8*i+5)*8+p]
                      + x1.z * spd[(8*i+6)*8+p] + x1.w * spd[(8*i+7)*8+p];
            }
            uint4 u;
            u.x = pack2(x0.x, x0.y); u.y = pack2(x0.z, x0.w);
            u.z = pack2(x1.x, x1.y); u.w = pack2(x1.z, x1.w);
            *(uint4*)(kbf + base + i * 8) = u;
        }
        int bits = 0;
#pragma unroll
        for (int p = 0; p < 8; ++p) bits |= (d[p] > 0.f) ? (1 << p) : 0;
        ht[1][h][sl] = bits ^ (bits >> 1);
    }
    // ---- V: bf16 write only ----
#pragma unroll
    for (int i = 0; i < 8; ++i) {
        float4 x0 = ((const float4*)(v + base + i * 8))[0];
        float4 x1 = ((const float4*)(v + base + i * 8))[1];
        uint4 u;
        u.x = pack2(x0.x, x0.y); u.y = pack2(x0.z, x0.w);
        u.z = pack2(x1.x, x1.y); u.w = pack2(x1.z, x1.w);
        *(uint4*)(vbf + base + i * 8) = u;
    }
    __syncthreads();

    if (t < 128) {       // 2 arrays x 16 h x 4 int4 = 128 coalesced stores
        const int inp = t >> 6, r = t & 63, h2 = r >> 2, p2 = r & 3;
        int4 val = *(const int4*)&ht[inp][h2][p2 * 4];
        int* dst = inp ? hk : hq;
        *(int4*)&dst[(b * H + h2) * S + s0 + p2 * 4] = val;
    }
}

// ---------------------------------------------------------------------------
// Kernel 2: stable counting sort (argsort) of hashes per (b,h).  (unchanged)
// ---------------------------------------------------------------------------
#define SORT_NT 64
#define SORT_CH (S / SORT_NT)   // 128

__global__ __launch_bounds__(SORT_NT) void k_sort(const int* __restrict__ hq,
                                                  const int* __restrict__ hk,
                                                  int* __restrict__ qs,
                                                  int* __restrict__ ks) {
    __shared__ int hist[SORT_NT * 256];
    __shared__ int base[257];
    const int t  = threadIdx.x;
    const int bh = blockIdx.x & (BH - 1);
    const bool isQ = blockIdx.x < BH;
    const int* hp = (isQ ? hq : hk) + bh * S;
    int*       sp = (isQ ? qs : ks) + bh * S;

    for (int i = 0; i < 256; ++i) hist[t * 256 + i] = 0;
    __syncthreads();
    for (int i = 0; i < SORT_CH; ++i) hist[t * 256 + hp[t * SORT_CH + i]]++;
    __syncthreads();

    for (int bi = 0; bi < 4; ++bi) {
        const int bin = t * 4 + bi;
        int sum = 0;
        for (int tt = 0; tt < SORT_NT; ++tt) sum += hist[tt * 256 + bin];
        base[bin + 1] = sum;
    }
    __syncthreads();
    if (t == 0) {
        base[0] = 0;
        for (int i = 1; i <= 256; ++i) base[i] += base[i - 1];
    }
    __syncthreads();

    for (int bi = 0; bi < 4; ++bi) {
        const int bin = t * 4 + bi;
        int run = base[bin];
        for (int tt = 0; tt < SORT_NT; ++tt) {
            int c = hist[tt * 256 + bin];
            hist[tt * 256 + bin] = run;
            run += c;
        }
    }
    __syncthreads();

    for (int i = 0; i < SORT_CH; ++i) {
        const int s0  = t * SORT_CH + i;
        const int bin = hp[s0];
        sp[hist[t * 256 + bin]++] = s0;
    }
}

// ---------------------------------------------------------------------------
// Kernel 3: FUSED attention on precomputed bf16 (R3 structure).
// One online softmax over 512 keys (pass0 = LSH block keys, pass1 = sampled
// keys with +LOG32 bias).  Swapped QK^T: c = mfma(A=K, B=Q) -> lane(lg,lr)
// holds P[query=lr][key=kg*16+lg*4+r].  PV: A=P, B=V^T.
// 512 thr = 8 waves x 32 queries.  XCD-aware block swizzle (nwg=1024).
// ---------------------------------------------------------------------------
#define VP 264    // vT pitch (256 + 8 pad)
#define PP 40     // per-wave P pitch (32 + 8 pad)

__global__ __launch_bounds__(512, 4) void k_attn(const unsigned short* __restrict__ qbf,
                                                 const unsigned short* __restrict__ kbf,
                                                 const unsigned short* __restrict__ vbf,
                                                 const int* __restrict__ qs,
                                                 const int* __restrict__ ks,
                                                 const int* __restrict__ sidx,
                                                 float* __restrict__ out) {
    __shared__ __align__(16) unsigned short vT[64 * VP];
    __shared__ __align__(16) unsigned short pL[8 * 32 * PP];

    const int t    = threadIdx.x;
    const int w    = t >> 6;
    const int lane = t & 63;
    const int lg   = lane >> 4;      // 0..3
    const int lr   = lane & 15;      // 0..15
    // XCD swizzle: all 32 blocks of one (b,h) land on one XCD (1024 % 8 == 0)
    const int logical = (blockIdx.x & 7) * (BH * NB / 8) + (blockIdx.x >> 3);
    const int blk  = logical & (NB - 1);
    const int bh   = logical >> 5;
    const int h    = bh & (H - 1), b = bh >> 4;
    const int sbase = bh * S + blk * BS;
    unsigned short* pw = pL + w * 32 * PP;

    // ---- Q B-fragments (pre-scaled bf16) + query rows ----
    int qrow[2]; bf16x8 bq[2][2];
#pragma unroll
    for (int qg = 0; qg < 2; ++qg) {
        qrow[qg] = qs[sbase + w * 32 + qg * 16 + lr];
        const unsigned short* qp = qbf + (((b * S + qrow[qg]) * H + h) << 6);
        bq[qg][0] = *(const bf16x8*)(qp + lg * 8);
        bq[qg][1] = *(const bf16x8*)(qp + 32 + lg * 8);
    }

    float m_run[2] = {-1e30f, -1e30f}, l_run[2] = {0.f, 0.f};
    f32x4 acc[2][4];
#pragma unroll
    for (int qg = 0; qg < 2; ++qg)
#pragma unroll
        for (int dg = 0; dg < 4; ++dg) acc[qg][dg] = (f32x4){0.f, 0.f, 0.f, 0.f};

    for (int pass = 0; pass < 2; ++pass) {
        if (pass) __syncthreads();              // all reads of old vT done
        {   // ---- stage V^T (bf16, transpose scatter) ----
            const int key = t >> 1, d0 = (t & 1) * 32;
            const int krow = pass ? sidx[bh * SAMP + key] : ks[sbase + key];
            const unsigned short* vp = vbf + (((b * S + krow) * H + h) << 6) + d0;
#pragma unroll
            for (int i = 0; i < 4; ++i) {
                uint4 x = *(const uint4*)(vp + i * 8);
                const int d = d0 + i * 8;
                vT[(d + 0) * VP + key] = (unsigned short)(x.x);
                vT[(d + 1) * VP + key] = (unsigned short)(x.x >> 16);
                vT[(d + 2) * VP + key] = (unsigned short)(x.y);
                vT[(d + 3) * VP + key] = (unsigned short)(x.y >> 16);
                vT[(d + 4) * VP + key] = (unsigned short)(x.z);
                vT[(d + 5) * VP + key] = (unsigned short)(x.z >> 16);
                vT[(d + 6) * VP + key] = (unsigned short)(x.w);
                vT[(d + 7) * VP + key] = (unsigned short)(x.w >> 16);
            }
        }
        __syncthreads();

        const float bias = pass ? LOG32 : 0.f;
        for (int kt4 = 0; kt4 < 4; ++kt4) {
            // ---- gathered key rows ----
            int krw[4];
#pragma unroll
            for (int kg = 0; kg < 4; ++kg) {
                const int key = kt4 * 64 + kg * 16 + lr;
                krw[kg] = pass ? sidx[bh * SAMP + key] : ks[sbase + key];
            }
            // ---- S^T = K Q^T  (A=K frags, B=Q frags) ----
            f32x4 c[2][4];
#pragma unroll
            for (int kf = 0; kf < 2; ++kf) {
                bf16x8 ak[4];
#pragma unroll
                for (int kg = 0; kg < 4; ++kg)
                    ak[kg] = *(const bf16x8*)(kbf + (((b * S + krw[kg]) * H + h) << 6)
                                              + kf * 32 + lg * 8);
#pragma unroll
                for (int qg = 0; qg < 2; ++qg)
#pragma unroll
                    for (int kg = 0; kg < 4; ++kg) {
                        f32x4 cin = kf ? c[qg][kg] : (f32x4){0.f, 0.f, 0.f, 0.f};
                        c[qg][kg] = __builtin_amdgcn_mfma_f32_16x16x32_bf16(ak[kg], bq[qg][kf], cin, 0, 0, 0);
                    }
            }
            // ---- online softmax: keys mostly in-lane ----
            float esc[2];
#pragma unroll
            for (int qg = 0; qg < 2; ++qg) {
                float tm = -1e30f;
#pragma unroll
                for (int kg = 0; kg < 4; ++kg)
#pragma unroll
                    for (int r = 0; r < 4; ++r) tm = fmaxf(tm, c[qg][kg][r]);
                tm = fmaxf(tm, __shfl_xor(tm, 16));
                tm = fmaxf(tm, __shfl_xor(tm, 32));
                tm += bias;
                const float mn = fmaxf(m_run[qg], tm);
                esc[qg] = __expf(m_run[qg] - mn);
                m_run[qg] = mn;
                const float mnb = mn - bias;
                float rs = 0.f;
#pragma unroll
                for (int kg = 0; kg < 4; ++kg)
#pragma unroll
                    for (int r = 0; r < 4; ++r) {
                        const float p = __expf(c[qg][kg][r] - mnb);
                        c[qg][kg][r] = p;
                        rs += p;
                    }
                rs += __shfl_xor(rs, 16);
                rs += __shfl_xor(rs, 32);
                l_run[qg] = l_run[qg] * esc[qg] + rs;
            }
            // ---- rescale acc (esc lives per query=lr; acc rows = lg*4+r) ----
#pragma unroll
            for (int qg = 0; qg < 2; ++qg)
#pragma unroll
                for (int r = 0; r < 4; ++r) {
                    const float er = __shfl(esc[qg], lg * 4 + r);
#pragma unroll
                    for (int dg = 0; dg < 4; ++dg) acc[qg][dg][r] *= er;
                }
            // ---- PV in 32-key halves: packed P write, b128 reads ----
#pragma unroll
            for (int hh = 0; hh < 2; ++hh) {
#pragma unroll
                for (int qg = 0; qg < 2; ++qg)
#pragma unroll
                    for (int kg2 = 0; kg2 < 2; ++kg2) {
                        const int kg = hh * 2 + kg2;
                        uint2 u;
                        u.x = pack2(c[qg][kg][0], c[qg][kg][1]);
                        u.y = pack2(c[qg][kg][2], c[qg][kg][3]);
                        *(uint2*)&pw[(qg * 16 + lr) * PP + kg2 * 16 + lg * 4] = u;
                    }
                bf16x8 bv[4];
#pragma unroll
                for (int dg = 0; dg < 4; ++dg)
                    bv[dg] = *(const bf16x8*)&vT[(dg * 16 + lr) * VP + kt4 * 64 + hh * 32 + lg * 8];
#pragma unroll
                for (int qg = 0; qg < 2; ++qg) {
                    const bf16x8 ap = *(const bf16x8*)&pw[(qg * 16 + lr) * PP + lg * 8];
#pragma unroll
                    for (int dg = 0; dg < 4; ++dg)
                        acc[qg][dg] = __builtin_amdgcn_mfma_f32_16x16x32_bf16(ap, bv[dg], acc[qg][dg], 0, 0, 0);
                }
            }
        }
    }

    // ---- epilogue: out = acc / l, scattered to original query order ----
#pragma unroll
    for (int qg = 0; qg < 2; ++qg)
#pragma unroll
        for (int r = 0; r < 4; ++r) {
            const float lq = __shfl(l_run[qg], lg * 4 + r);
            const int   qr = __shfl(qrow[qg], lg * 4 + r);
            const float inv = 1.f / lq;
            const int obase = ((b * S + qr) * H + h) << 6;
#pragma unroll
            for (int dg = 0; dg < 4; ++dg)
                out[obase + dg * 16 + lr] = acc[qg][dg][r] * inv;
        }
}

// ---------------------------------------------------------------------------
extern "C" void kernel_launch(void* const* d_in, const int* in_sizes, int n_in,
                              void* d_out, int out_size, void* d_ws, size_t ws_size,
                              hipStream_t stream) {
    const float* q   = (const float*)d_in[0];
    const float* k   = (const float*)d_in[1];
    const float* v   = (const float*)d_in[2];
    const float* pd  = (const float*)d_in[3];
    const int*  sidx = (const int*)d_in[4];
    float* out = (float*)d_out;

    int* hq = (int*)d_ws;
    int* hk = hq + BHS;
    int* qs = hk + BHS;
    int* ks = qs + BHS;
    unsigned short* qbf = (unsigned short*)(ks + BHS);
    unsigned short* kbf = qbf + BSHD;
    unsigned short* vbf = kbf + BSHD;

    k_prep<<<B * (S / 16), 256, 0, stream>>>(q, k, v, pd, hq, hk, qbf, kbf, vbf);
    k_sort<<<2 * BH, SORT_NT, 0, stream>>>(hq, hk, qs, ks);
    k_attn<<<BH * NB, 512, 0, stream>>>(qbf, kbf, vbf, qs, ks, sidx, out);
}

// Round 6
// 379.443 us; speedup vs baseline: 1.2322x; 1.2322x over previous
//
#include <hip/hip_runtime.h>
#include <hip/hip_bf16.h>

#define B 2
#define S 8192
#define H 16
#define D 64
#define NB 32          // S / BS
#define BS 256
#define SAMP 256
#define BH (B*H)
#define BHS (B*H*S)
#define BSHD (B*S*H*D)
#define LOG32 3.4657359027997265f   // log(8192/256)

typedef float f32x4 __attribute__((ext_vector_type(4)));
typedef short bf16x8 __attribute__((ext_vector_type(8)));

__device__ __forceinline__ unsigned short f2bf(float x) {
    unsigned int u = __builtin_bit_cast(unsigned int, x);
    u += 0x7fffu + ((u >> 16) & 1u);       // round-to-nearest-even
    return (unsigned short)(u >> 16);
}
__device__ __forceinline__ unsigned int pack2(float a, float b) {
    return (unsigned int)f2bf(a) | ((unsigned int)f2bf(b) << 16);
}

// ---------------------------------------------------------------------------
// Kernel 1: LSH hash of Q,K + bf16 pre-conversion of K,V (single fused loop,
// R3's register-friendly structure; VGPR pinned by __launch_bounds__(256,3)).
// Block = 256 thr = 16 s x 16 h -> wave footprint contiguous 16 KB
// (lane stride 256 B).  Q is NOT converted here (attn reads it once, f32).
// Hash writes staged via LDS, out as coalesced int4.
// ---------------------------------------------------------------------------
__global__ __launch_bounds__(256, 3) void k_prep(const float* __restrict__ q,
                                                 const float* __restrict__ k,
                                                 const float* __restrict__ v,
                                                 const float* __restrict__ pd,
                                                 int* __restrict__ hq,
                                                 int* __restrict__ hk,
                                                 unsigned short* __restrict__ kbf,
                                                 unsigned short* __restrict__ vbf) {
    __shared__ float spd[D * 8];
    __shared__ int   ht[2][16][16];   // [q/k][h][s_local]
    const int t = threadIdx.x;
    for (int i = t; i < D * 8; i += 256) spd[i] = pd[i];
    __syncthreads();

    const int b  = blockIdx.x >> 9;        // 512 s-chunks per batch
    const int s0 = (blockIdx.x & 511) * 16;
    const int sl = t >> 4;                 // s_local 0..15
    const int h  = t & 15;
    const int base = ((b * S + s0 + sl) * H + h) << 6;

    float dq[8], dk[8];
#pragma unroll
    for (int p = 0; p < 8; ++p) { dq[p] = 0.f; dk[p] = 0.f; }

#pragma unroll
    for (int i = 0; i < 8; ++i) {
        // Q: hash accumulate only
        float4 x0 = ((const float4*)(q + base + i * 8))[0];
        float4 x1 = ((const float4*)(q + base + i * 8))[1];
#pragma unroll
        for (int p = 0; p < 8; ++p) {
            dq[p] += x0.x * spd[(8*i+0)*8+p] + x0.y * spd[(8*i+1)*8+p]
                   + x0.z * spd[(8*i+2)*8+p] + x0.w * spd[(8*i+3)*8+p]
                   + x1.x * spd[(8*i+4)*8+p] + x1.y * spd[(8*i+5)*8+p]
                   + x1.z * spd[(8*i+6)*8+p] + x1.w * spd[(8*i+7)*8+p];
        }
        // K: hash accumulate + bf16 pack/store
        float4 y0 = ((const float4*)(k + base + i * 8))[0];
        float4 y1 = ((const float4*)(k + base + i * 8))[1];
#pragma unroll
        for (int p = 0; p < 8; ++p) {
            dk[p] += y0.x * spd[(8*i+0)*8+p] + y0.y * spd[(8*i+1)*8+p]
                   + y0.z * spd[(8*i+2)*8+p] + y0.w * spd[(8*i+3)*8+p]
                   + y1.x * spd[(8*i+4)*8+p] + y1.y * spd[(8*i+5)*8+p]
                   + y1.z * spd[(8*i+6)*8+p] + y1.w * spd[(8*i+7)*8+p];
        }
        uint4 uk;
        uk.x = pack2(y0.x, y0.y); uk.y = pack2(y0.z, y0.w);
        uk.z = pack2(y1.x, y1.y); uk.w = pack2(y1.z, y1.w);
        *(uint4*)(kbf + base + i * 8) = uk;
        // V: bf16 pack/store
        float4 z0 = ((const float4*)(v + base + i * 8))[0];
        float4 z1 = ((const float4*)(v + base + i * 8))[1];
        uint4 uv;
        uv.x = pack2(z0.x, z0.y); uv.y = pack2(z0.z, z0.w);
        uv.z = pack2(z1.x, z1.y); uv.w = pack2(z1.z, z1.w);
        *(uint4*)(vbf + base + i * 8) = uv;
    }
    int bq = 0, bk = 0;
#pragma unroll
    for (int p = 0; p < 8; ++p) {
        bq |= (dq[p] > 0.f) ? (1 << p) : 0;
        bk |= (dk[p] > 0.f) ? (1 << p) : 0;
    }
    ht[0][h][sl] = bq ^ (bq >> 1);
    ht[1][h][sl] = bk ^ (bk >> 1);
    __syncthreads();

    if (t < 128) {       // 2 arrays x 16 h x 4 int4 = 128 coalesced stores
        const int inp = t >> 6, r = t & 63, h2 = r >> 2, p2 = r & 3;
        int4 val = *(const int4*)&ht[inp][h2][p2 * 4];
        int* dst = inp ? hk : hq;
        *(int4*)&dst[(b * H + h2) * S + s0 + p2 * 4] = val;
    }
}

// ---------------------------------------------------------------------------
// Kernel 2: stable counting sort (argsort) of hashes per (b,h).  (unchanged)
// ---------------------------------------------------------------------------
#define SORT_NT 64
#define SORT_CH (S / SORT_NT)   // 128

__global__ __launch_bounds__(SORT_NT) void k_sort(const int* __restrict__ hq,
                                                  const int* __restrict__ hk,
                                                  int* __restrict__ qs,
                                                  int* __restrict__ ks) {
    __shared__ int hist[SORT_NT * 256];
    __shared__ int base[257];
    const int t  = threadIdx.x;
    const int bh = blockIdx.x & (BH - 1);
    const bool isQ = blockIdx.x < BH;
    const int* hp = (isQ ? hq : hk) + bh * S;
    int*       sp = (isQ ? qs : ks) + bh * S;

    for (int i = 0; i < 256; ++i) hist[t * 256 + i] = 0;
    __syncthreads();
    for (int i = 0; i < SORT_CH; ++i) hist[t * 256 + hp[t * SORT_CH + i]]++;
    __syncthreads();

    for (int bi = 0; bi < 4; ++bi) {
        const int bin = t * 4 + bi;
        int sum = 0;
        for (int tt = 0; tt < SORT_NT; ++tt) sum += hist[tt * 256 + bin];
        base[bin + 1] = sum;
    }
    __syncthreads();
    if (t == 0) {
        base[0] = 0;
        for (int i = 1; i <= 256; ++i) base[i] += base[i - 1];
    }
    __syncthreads();

    for (int bi = 0; bi < 4; ++bi) {
        const int bin = t * 4 + bi;
        int run = base[bin];
        for (int tt = 0; tt < SORT_NT; ++tt) {
            int c = hist[tt * 256 + bin];
            hist[tt * 256 + bin] = run;
            run += c;
        }
    }
    __syncthreads();

    for (int i = 0; i < SORT_CH; ++i) {
        const int s0  = t * SORT_CH + i;
        const int bin = hp[s0];
        sp[hist[t * 256 + bin]++] = s0;
    }
}

// ---------------------------------------------------------------------------
// Kernel 3: FUSED attention.  Q from f32 (inline cvt, read once); K/V from
// precomputed bf16 (compact gathers).  One online softmax over 512 keys
// (pass0 = LSH block keys, pass1 = sampled keys with +LOG32 bias).
// Swapped QK^T: c = mfma(A=K, B=Q) -> lane(lg,lr) holds
// P[query=lr][key=kg*16+lg*4+r].  Defer-max (THR=8) skips acc rescale.
// 512 thr = 8 waves x 32 queries.  XCD-aware block swizzle (1024 % 8 == 0).
// ---------------------------------------------------------------------------
#define VP 264    // vT pitch (256 + 8 pad)
#define PP 40     // per-wave P pitch (32 + 8 pad)

__global__ __launch_bounds__(512, 4) void k_attn(const float* __restrict__ q,
                                                 const unsigned short* __restrict__ kbf,
                                                 const unsigned short* __restrict__ vbf,
                                                 const int* __restrict__ qs,
                                                 const int* __restrict__ ks,
                                                 const int* __restrict__ sidx,
                                                 float* __restrict__ out) {
    __shared__ __align__(16) unsigned short vT[64 * VP];
    __shared__ __align__(16) unsigned short pL[8 * 32 * PP];

    const int t    = threadIdx.x;
    const int w    = t >> 6;
    const int lane = t & 63;
    const int lg   = lane >> 4;      // 0..3
    const int lr   = lane & 15;      // 0..15
    // XCD swizzle: all 32 blocks of one (b,h) land on one XCD
    const int logical = (blockIdx.x & 7) * (BH * NB / 8) + (blockIdx.x >> 3);
    const int blk  = logical & (NB - 1);
    const int bh   = logical >> 5;
    const int h    = bh & (H - 1), b = bh >> 4;
    const int sbase = bh * S + blk * BS;
    unsigned short* pw = pL + w * 32 * PP;

    // ---- Q B-fragments from f32 (scale 1/8 folded into cvt) ----
    int qrow[2]; bf16x8 bq[2][2];
#pragma unroll
    for (int qg = 0; qg < 2; ++qg) {
        qrow[qg] = qs[sbase + w * 32 + qg * 16 + lr];
        const float* qp = q + (((b * S + qrow[qg]) * H + h) << 6);
#pragma unroll
        for (int kf = 0; kf < 2; ++kf) {
            float4 x0 = ((const float4*)(qp + kf * 32 + lg * 8))[0];
            float4 x1 = ((const float4*)(qp + kf * 32 + lg * 8))[1];
            union { bf16x8 v8; unsigned int u[4]; } fa;
            fa.u[0] = pack2(x0.x * 0.125f, x0.y * 0.125f);
            fa.u[1] = pack2(x0.z * 0.125f, x0.w * 0.125f);
            fa.u[2] = pack2(x1.x * 0.125f, x1.y * 0.125f);
            fa.u[3] = pack2(x1.z * 0.125f, x1.w * 0.125f);
            bq[qg][kf] = fa.v8;
        }
    }

    float m_run[2] = {-1e30f, -1e30f}, l_run[2] = {0.f, 0.f};
    f32x4 acc[2][4];
#pragma unroll
    for (int qg = 0; qg < 2; ++qg)
#pragma unroll
        for (int dg = 0; dg < 4; ++dg) acc[qg][dg] = (f32x4){0.f, 0.f, 0.f, 0.f};

    for (int pass = 0; pass < 2; ++pass) {
        if (pass) __syncthreads();              // all reads of old vT done
        {   // ---- stage V^T (bf16, transpose scatter) ----
            const int key = t >> 1, d0 = (t & 1) * 32;
            const int krow = pass ? sidx[bh * SAMP + key] : ks[sbase + key];
            const unsigned short* vp = vbf + (((b * S + krow) * H + h) << 6) + d0;
#pragma unroll
            for (int i = 0; i < 4; ++i) {
                uint4 x = *(const uint4*)(vp + i * 8);
                const int d = d0 + i * 8;
                vT[(d + 0) * VP + key] = (unsigned short)(x.x);
                vT[(d + 1) * VP + key] = (unsigned short)(x.x >> 16);
                vT[(d + 2) * VP + key] = (unsigned short)(x.y);
                vT[(d + 3) * VP + key] = (unsigned short)(x.y >> 16);
                vT[(d + 4) * VP + key] = (unsigned short)(x.z);
                vT[(d + 5) * VP + key] = (unsigned short)(x.z >> 16);
                vT[(d + 6) * VP + key] = (unsigned short)(x.w);
                vT[(d + 7) * VP + key] = (unsigned short)(x.w >> 16);
            }
        }
        __syncthreads();

        const float bias = pass ? LOG32 : 0.f;
        for (int kt4 = 0; kt4 < 4; ++kt4) {
            // ---- gathered key rows ----
            int krw[4];
#pragma unroll
            for (int kg = 0; kg < 4; ++kg) {
                const int key = kt4 * 64 + kg * 16 + lr;
                krw[kg] = pass ? sidx[bh * SAMP + key] : ks[sbase + key];
            }
            // ---- S^T = K Q^T  (A=K frags, B=Q frags) ----
            f32x4 c[2][4];
#pragma unroll
            for (int kf = 0; kf < 2; ++kf) {
                bf16x8 ak[4];
#pragma unroll
                for (int kg = 0; kg < 4; ++kg)
                    ak[kg] = *(const bf16x8*)(kbf + (((b * S + krw[kg]) * H + h) << 6)
                                              + kf * 32 + lg * 8);
#pragma unroll
                for (int qg = 0; qg < 2; ++qg)
#pragma unroll
                    for (int kg = 0; kg < 4; ++kg) {
                        f32x4 cin = kf ? c[qg][kg] : (f32x4){0.f, 0.f, 0.f, 0.f};
                        c[qg][kg] = __builtin_amdgcn_mfma_f32_16x16x32_bf16(ak[kg], bq[qg][kf], cin, 0, 0, 0);
                    }
            }
            // ---- online softmax with defer-max (keys in-lane) ----
#pragma unroll
            for (int qg = 0; qg < 2; ++qg) {
                float tm = -1e30f;
#pragma unroll
                for (int kg = 0; kg < 4; ++kg)
#pragma unroll
                    for (int r = 0; r < 4; ++r) tm = fmaxf(tm, c[qg][kg][r]);
                tm = fmaxf(tm, __shfl_xor(tm, 16));
                tm = fmaxf(tm, __shfl_xor(tm, 32));
                tm += bias;
                if (!__all(tm <= m_run[qg] + 8.f)) {
                    const float mn  = fmaxf(m_run[qg], tm);
                    const float es  = __expf(m_run[qg] - mn);
                    m_run[qg] = mn;
                    l_run[qg] *= es;
#pragma unroll
                    for (int r = 0; r < 4; ++r) {
                        const float er = __shfl(es, lg * 4 + r);
#pragma unroll
                        for (int dg = 0; dg < 4; ++dg) acc[qg][dg][r] *= er;
                    }
                }
                const float mnb = m_run[qg] - bias;
                float rs = 0.f;
#pragma unroll
                for (int kg = 0; kg < 4; ++kg)
#pragma unroll
                    for (int r = 0; r < 4; ++r) {
                        const float p = __expf(c[qg][kg][r] - mnb);
                        c[qg][kg][r] = p;
                        rs += p;
                    }
                rs += __shfl_xor(rs, 16);
                rs += __shfl_xor(rs, 32);
                l_run[qg] += rs;
            }
            // ---- PV in 32-key halves: packed P write, b128 reads ----
#pragma unroll
            for (int hh = 0; hh < 2; ++hh) {
#pragma unroll
                for (int qg = 0; qg < 2; ++qg)
#pragma unroll
                    for (int kg2 = 0; kg2 < 2; ++kg2) {
                        const int kg = hh * 2 + kg2;
                        uint2 u;
                        u.x = pack2(c[qg][kg][0], c[qg][kg][1]);
                        u.y = pack2(c[qg][kg][2], c[qg][kg][3]);
                        *(uint2*)&pw[(qg * 16 + lr) * PP + kg2 * 16 + lg * 4] = u;
                    }
                bf16x8 bv[4];
#pragma unroll
                for (int dg = 0; dg < 4; ++dg)
                    bv[dg] = *(const bf16x8*)&vT[(dg * 16 + lr) * VP + kt4 * 64 + hh * 32 + lg * 8];
#pragma unroll
                for (int qg = 0; qg < 2; ++qg) {
                    const bf16x8 ap = *(const bf16x8*)&pw[(qg * 16 + lr) * PP + lg * 8];
#pragma unroll
                    for (int dg = 0; dg < 4; ++dg)
                        acc[qg][dg] = __builtin_amdgcn_mfma_f32_16x16x32_bf16(ap, bv[dg], acc[qg][dg], 0, 0, 0);
                }
            }
        }
    }

    // ---- epilogue: out = acc / l, scattered to original query order ----
#pragma unroll
    for (int qg = 0; qg < 2; ++qg)
#pragma unroll
        for (int r = 0; r < 4; ++r) {
            const float lq = __shfl(l_run[qg], lg * 4 + r);
            const int   qr = __shfl(qrow[qg], lg * 4 + r);
            const float inv = 1.f / lq;
            const int obase = ((b * S + qr) * H + h) << 6;
#pragma unroll
            for (int dg = 0; dg < 4; ++dg)
                out[obase + dg * 16 + lr] = acc[qg][dg][r] * inv;
        }
}

// ---------------------------------------------------------------------------
extern "C" void kernel_launch(void* const* d_in, const int* in_sizes, int n_in,
                              void* d_out, int out_size, void* d_ws, size_t ws_size,
                              hipStream_t stream) {
    const float* q   = (const float*)d_in[0];
    const float* k   = (const float*)d_in[1];
    const float* v   = (const float*)d_in[2];
    const float* pd  = (const float*)d_in[3];
    const int*  sidx = (const int*)d_in[4];
    float* out = (float*)d_out;

    int* hq = (int*)d_ws;
    int* hk = hq + BHS;
    int* qs = hk + BHS;
    int* ks = qs + BHS;
    unsigned short* kbf = (unsigned short*)(ks + BHS);
    unsigned short* vbf = kbf + BSHD;

    k_prep<<<B * (S / 16), 256, 0, stream>>>(q, k, v, pd, hq, hk, kbf, vbf);
    k_sort<<<2 * BH, SORT_NT, 0, stream>>>(hq, hk, qs, ks);
    k_attn<<<BH * NB, 512, 0, stream>>>(q, kbf, vbf, qs, ks, sidx, out);
}

// Round 7
// 287.454 us; speedup vs baseline: 1.6266x; 1.3200x over previous
//
#include <hip/hip_runtime.h>
#include <hip/hip_bf16.h>

#define B 2
#define S 8192
#define H 16
#define D 64
#define NB 32          // S / BS
#define BS 256
#define SAMP 256
#define BH (B*H)
#define BHS (B*H*S)
#define BSHD (B*S*H*D)
#define LOG32 3.4657359027997265f   // log(8192/256)

typedef float f32x4 __attribute__((ext_vector_type(4)));
typedef short bf16x8 __attribute__((ext_vector_type(8)));

__device__ __forceinline__ unsigned short f2bf(float x) {
    unsigned int u = __builtin_bit_cast(unsigned int, x);
    u += 0x7fffu + ((u >> 16) & 1u);       // round-to-nearest-even
    return (unsigned short)(u >> 16);
}
__device__ __forceinline__ unsigned int pack2(float a, float b) {
    return (unsigned int)f2bf(a) | ((unsigned int)f2bf(b) << 16);
}

// ---------------------------------------------------------------------------
// Kernel 1: LSH hash of Q,K + bf16 conversion of K,V.  QUAD-COOPERATIVE:
// 4 lanes own one row (lane c holds dims {j*16+c*4+u}); per-instruction wave
// footprint = 16 x 64B fully-consumed chunks (vs 64 x 16B at 256B stride in
// R6, which over-fetched 2.3x).  Quad shfl_xor reduce completes the dots;
// lane c keeps row (quad_base + c) -> hash stores are lane-contiguous.
// ---------------------------------------------------------------------------
__global__ __launch_bounds__(256, 4) void k_prep(const float* __restrict__ q,
                                                 const float* __restrict__ k,
                                                 const float* __restrict__ v,
                                                 const float* __restrict__ pd,
                                                 int* __restrict__ hq,
                                                 int* __restrict__ hk,
                                                 unsigned short* __restrict__ kbf,
                                                 unsigned short* __restrict__ vbf) {
    __shared__ float spd[D * 8];
    const int t = threadIdx.x;
    for (int i = t; i < D * 8; i += 256) spd[i] = pd[i];
    __syncthreads();

    const int lane = t & 63;
    const int c    = lane & 3;                         // dim-quarter owner
    const int rowq = blockIdx.x * 256 + (t >> 6) * 64 + (lane >> 2) * 4;
    const int myrow = rowq + c;                        // row this lane emits
    // row r -> (b,s,h):  r = (b*S + s)*H + h ;  S*H = 2^17, H = 16
    const int mb = myrow >> 17, ms = (myrow >> 4) & (S - 1), mh = myrow & (H - 1);
    const int hout = (mb * H + mh) * S + ms;

    float d[4][8];

    // ================= Q: hash only =================
#pragma unroll
    for (int rr = 0; rr < 4; ++rr)
#pragma unroll
        for (int p = 0; p < 8; ++p) d[rr][p] = 0.f;

#pragma unroll
    for (int j = 0; j < 4; ++j) {
        float4 x[4];
#pragma unroll
        for (int rr = 0; rr < 4; ++rr)
            x[rr] = *(const float4*)(q + ((rowq + rr) << 6) + j * 16 + c * 4);
#pragma unroll
        for (int u = 0; u < 4; ++u) {
            const int dim = j * 16 + c * 4 + u;
            float4 s0 = *(const float4*)&spd[dim * 8];
            float4 s1 = *(const float4*)&spd[dim * 8 + 4];
#pragma unroll
            for (int rr = 0; rr < 4; ++rr) {
                const float xv = (u == 0) ? x[rr].x : (u == 1) ? x[rr].y
                               : (u == 2) ? x[rr].z : x[rr].w;
                d[rr][0] += xv * s0.x; d[rr][1] += xv * s0.y;
                d[rr][2] += xv * s0.z; d[rr][3] += xv * s0.w;
                d[rr][4] += xv * s1.x; d[rr][5] += xv * s1.y;
                d[rr][6] += xv * s1.z; d[rr][7] += xv * s1.w;
            }
        }
    }
#pragma unroll
    for (int rr = 0; rr < 4; ++rr)
#pragma unroll
        for (int p = 0; p < 8; ++p) {
            d[rr][p] += __shfl_xor(d[rr][p], 1);
            d[rr][p] += __shfl_xor(d[rr][p], 2);
        }
    {
        int bits[4];
#pragma unroll
        for (int rr = 0; rr < 4; ++rr) {
            int bv = 0;
#pragma unroll
            for (int p = 0; p < 8; ++p) bv |= (d[rr][p] > 0.f) ? (1 << p) : 0;
            bits[rr] = bv;
        }
        const int myb = (c == 0) ? bits[0] : (c == 1) ? bits[1]
                      : (c == 2) ? bits[2] : bits[3];
        hq[hout] = myb ^ (myb >> 1);
    }

    // ================= K: hash + bf16 pack =================
#pragma unroll
    for (int rr = 0; rr < 4; ++rr)
#pragma unroll
        for (int p = 0; p < 8; ++p) d[rr][p] = 0.f;

#pragma unroll
    for (int j = 0; j < 4; ++j) {
        float4 x[4];
#pragma unroll
        for (int rr = 0; rr < 4; ++rr)
            x[rr] = *(const float4*)(k + ((rowq + rr) << 6) + j * 16 + c * 4);
#pragma unroll
        for (int rr = 0; rr < 4; ++rr) {
            uint2 u2;
            u2.x = pack2(x[rr].x, x[rr].y);
            u2.y = pack2(x[rr].z, x[rr].w);
            *(uint2*)(kbf + ((rowq + rr) << 6) + j * 16 + c * 4) = u2;
        }
#pragma unroll
        for (int u = 0; u < 4; ++u) {
            const int dim = j * 16 + c * 4 + u;
            float4 s0 = *(const float4*)&spd[dim * 8];
            float4 s1 = *(const float4*)&spd[dim * 8 + 4];
#pragma unroll
            for (int rr = 0; rr < 4; ++rr) {
                const float xv = (u == 0) ? x[rr].x : (u == 1) ? x[rr].y
                               : (u == 2) ? x[rr].z : x[rr].w;
                d[rr][0] += xv * s0.x; d[rr][1] += xv * s0.y;
                d[rr][2] += xv * s0.z; d[rr][3] += xv * s0.w;
                d[rr][4] += xv * s1.x; d[rr][5] += xv * s1.y;
                d[rr][6] += xv * s1.z; d[rr][7] += xv * s1.w;
            }
        }
    }
#pragma unroll
    for (int rr = 0; rr < 4; ++rr)
#pragma unroll
        for (int p = 0; p < 8; ++p) {
            d[rr][p] += __shfl_xor(d[rr][p], 1);
            d[rr][p] += __shfl_xor(d[rr][p], 2);
        }
    {
        int bits[4];
#pragma unroll
        for (int rr = 0; rr < 4; ++rr) {
            int bv = 0;
#pragma unroll
            for (int p = 0; p < 8; ++p) bv |= (d[rr][p] > 0.f) ? (1 << p) : 0;
            bits[rr] = bv;
        }
        const int myb = (c == 0) ? bits[0] : (c == 1) ? bits[1]
                      : (c == 2) ? bits[2] : bits[3];
        hk[hout] = myb ^ (myb >> 1);
    }

    // ================= V: bf16 pack only =================
#pragma unroll
    for (int j = 0; j < 4; ++j) {
#pragma unroll
        for (int rr = 0; rr < 4; ++rr) {
            float4 x = *(const float4*)(v + ((rowq + rr) << 6) + j * 16 + c * 4);
            uint2 u2;
            u2.x = pack2(x.x, x.y);
            u2.y = pack2(x.z, x.w);
            *(uint2*)(vbf + ((rowq + rr) << 6) + j * 16 + c * 4) = u2;
        }
    }
}

// ---------------------------------------------------------------------------
// Kernel 2: stable counting sort (argsort) of hashes per (b,h).  (unchanged)
// ---------------------------------------------------------------------------
#define SORT_NT 64
#define SORT_CH (S / SORT_NT)   // 128

__global__ __launch_bounds__(SORT_NT) void k_sort(const int* __restrict__ hq,
                                                  const int* __restrict__ hk,
                                                  int* __restrict__ qs,
                                                  int* __restrict__ ks) {
    __shared__ int hist[SORT_NT * 256];
    __shared__ int base[257];
    const int t  = threadIdx.x;
    const int bh = blockIdx.x & (BH - 1);
    const bool isQ = blockIdx.x < BH;
    const int* hp = (isQ ? hq : hk) + bh * S;
    int*       sp = (isQ ? qs : ks) + bh * S;

    for (int i = 0; i < 256; ++i) hist[t * 256 + i] = 0;
    __syncthreads();
    for (int i = 0; i < SORT_CH; ++i) hist[t * 256 + hp[t * SORT_CH + i]]++;
    __syncthreads();

    for (int bi = 0; bi < 4; ++bi) {
        const int bin = t * 4 + bi;
        int sum = 0;
        for (int tt = 0; tt < SORT_NT; ++tt) sum += hist[tt * 256 + bin];
        base[bin + 1] = sum;
    }
    __syncthreads();
    if (t == 0) {
        base[0] = 0;
        for (int i = 1; i <= 256; ++i) base[i] += base[i - 1];
    }
    __syncthreads();

    for (int bi = 0; bi < 4; ++bi) {
        const int bin = t * 4 + bi;
        int run = base[bin];
        for (int tt = 0; tt < SORT_NT; ++tt) {
            int c = hist[tt * 256 + bin];
            hist[tt * 256 + bin] = run;
            run += c;
        }
    }
    __syncthreads();

    for (int i = 0; i < SORT_CH; ++i) {
        const int s0  = t * SORT_CH + i;
        const int bin = hp[s0];
        sp[hist[t * 256 + bin]++] = s0;
    }
}

// ---------------------------------------------------------------------------
// Kernel 3: FUSED attention (unchanged from R6).  Q from f32 (inline cvt,
// read once); K/V from precomputed bf16 (compact gathers).  One online
// softmax over 512 keys (pass0 = LSH block keys, pass1 = sampled keys with
// +LOG32 bias).  Swapped QK^T; defer-max (THR=8); XCD-aware block swizzle.
// ---------------------------------------------------------------------------
#define VP 264    // vT pitch (256 + 8 pad)
#define PP 40     // per-wave P pitch (32 + 8 pad)

__global__ __launch_bounds__(512, 4) void k_attn(const float* __restrict__ q,
                                                 const unsigned short* __restrict__ kbf,
                                                 const unsigned short* __restrict__ vbf,
                                                 const int* __restrict__ qs,
                                                 const int* __restrict__ ks,
                                                 const int* __restrict__ sidx,
                                                 float* __restrict__ out) {
    __shared__ __align__(16) unsigned short vT[64 * VP];
    __shared__ __align__(16) unsigned short pL[8 * 32 * PP];

    const int t    = threadIdx.x;
    const int w    = t >> 6;
    const int lane = t & 63;
    const int lg   = lane >> 4;      // 0..3
    const int lr   = lane & 15;      // 0..15
    // XCD swizzle: all 32 blocks of one (b,h) land on one XCD
    const int logical = (blockIdx.x & 7) * (BH * NB / 8) + (blockIdx.x >> 3);
    const int blk  = logical & (NB - 1);
    const int bh   = logical >> 5;
    const int h    = bh & (H - 1), b = bh >> 4;
    const int sbase = bh * S + blk * BS;
    unsigned short* pw = pL + w * 32 * PP;

    // ---- Q B-fragments from f32 (scale 1/8 folded into cvt) ----
    int qrow[2]; bf16x8 bq[2][2];
#pragma unroll
    for (int qg = 0; qg < 2; ++qg) {
        qrow[qg] = qs[sbase + w * 32 + qg * 16 + lr];
        const float* qp = q + (((b * S + qrow[qg]) * H + h) << 6);
#pragma unroll
        for (int kf = 0; kf < 2; ++kf) {
            float4 x0 = ((const float4*)(qp + kf * 32 + lg * 8))[0];
            float4 x1 = ((const float4*)(qp + kf * 32 + lg * 8))[1];
            union { bf16x8 v8; unsigned int u[4]; } fa;
            fa.u[0] = pack2(x0.x * 0.125f, x0.y * 0.125f);
            fa.u[1] = pack2(x0.z * 0.125f, x0.w * 0.125f);
            fa.u[2] = pack2(x1.x * 0.125f, x1.y * 0.125f);
            fa.u[3] = pack2(x1.z * 0.125f, x1.w * 0.125f);
            bq[qg][kf] = fa.v8;
        }
    }

    float m_run[2] = {-1e30f, -1e30f}, l_run[2] = {0.f, 0.f};
    f32x4 acc[2][4];
#pragma unroll
    for (int qg = 0; qg < 2; ++qg)
#pragma unroll
        for (int dg = 0; dg < 4; ++dg) acc[qg][dg] = (f32x4){0.f, 0.f, 0.f, 0.f};

    for (int pass = 0; pass < 2; ++pass) {
        if (pass) __syncthreads();              // all reads of old vT done
        {   // ---- stage V^T (bf16, transpose scatter) ----
            const int key = t >> 1, d0 = (t & 1) * 32;
            const int krow = pass ? sidx[bh * SAMP + key] : ks[sbase + key];
            const unsigned short* vp = vbf + (((b * S + krow) * H + h) << 6) + d0;
#pragma unroll
            for (int i = 0; i < 4; ++i) {
                uint4 x = *(const uint4*)(vp + i * 8);
                const int d = d0 + i * 8;
                vT[(d + 0) * VP + key] = (unsigned short)(x.x);
                vT[(d + 1) * VP + key] = (unsigned short)(x.x >> 16);
                vT[(d + 2) * VP + key] = (unsigned short)(x.y);
                vT[(d + 3) * VP + key] = (unsigned short)(x.y >> 16);
                vT[(d + 4) * VP + key] = (unsigned short)(x.z);
                vT[(d + 5) * VP + key] = (unsigned short)(x.z >> 16);
                vT[(d + 6) * VP + key] = (unsigned short)(x.w);
                vT[(d + 7) * VP + key] = (unsigned short)(x.w >> 16);
            }
        }
        __syncthreads();

        const float bias = pass ? LOG32 : 0.f;
        for (int kt4 = 0; kt4 < 4; ++kt4) {
            // ---- gathered key rows ----
            int krw[4];
#pragma unroll
            for (int kg = 0; kg < 4; ++kg) {
                const int key = kt4 * 64 + kg * 16 + lr;
                krw[kg] = pass ? sidx[bh * SAMP + key] : ks[sbase + key];
            }
            // ---- S^T = K Q^T  (A=K frags, B=Q frags) ----
            f32x4 c[2][4];
#pragma unroll
            for (int kf = 0; kf < 2; ++kf) {
                bf16x8 ak[4];
#pragma unroll
                for (int kg = 0; kg < 4; ++kg)
                    ak[kg] = *(const bf16x8*)(kbf + (((b * S + krw[kg]) * H + h) << 6)
                                              + kf * 32 + lg * 8);
#pragma unroll
                for (int qg = 0; qg < 2; ++qg)
#pragma unroll
                    for (int kg = 0; kg < 4; ++kg) {
                        f32x4 cin = kf ? c[qg][kg] : (f32x4){0.f, 0.f, 0.f, 0.f};
                        c[qg][kg] = __builtin_amdgcn_mfma_f32_16x16x32_bf16(ak[kg], bq[qg][kf], cin, 0, 0, 0);
                    }
            }
            // ---- online softmax with defer-max (keys in-lane) ----
#pragma unroll
            for (int qg = 0; qg < 2; ++qg) {
                float tm = -1e30f;
#pragma unroll
                for (int kg = 0; kg < 4; ++kg)
#pragma unroll
                    for (int r = 0; r < 4; ++r) tm = fmaxf(tm, c[qg][kg][r]);
                tm = fmaxf(tm, __shfl_xor(tm, 16));
                tm = fmaxf(tm, __shfl_xor(tm, 32));
                tm += bias;
                if (!__all(tm <= m_run[qg] + 8.f)) {
                    const float mn  = fmaxf(m_run[qg], tm);
                    const float es  = __expf(m_run[qg] - mn);
                    m_run[qg] = mn;
                    l_run[qg] *= es;
#pragma unroll
                    for (int r = 0; r < 4; ++r) {
                        const float er = __shfl(es, lg * 4 + r);
#pragma unroll
                        for (int dg = 0; dg < 4; ++dg) acc[qg][dg][r] *= er;
                    }
                }
                const float mnb = m_run[qg] - bias;
                float rs = 0.f;
#pragma unroll
                for (int kg = 0; kg < 4; ++kg)
#pragma unroll
                    for (int r = 0; r < 4; ++r) {
                        const float p = __expf(c[qg][kg][r] - mnb);
                        c[qg][kg][r] = p;
                        rs += p;
                    }
                rs += __shfl_xor(rs, 16);
                rs += __shfl_xor(rs, 32);
                l_run[qg] += rs;
            }
            // ---- PV in 32-key halves: packed P write, b128 reads ----
#pragma unroll
            for (int hh = 0; hh < 2; ++hh) {
#pragma unroll
                for (int qg = 0; qg < 2; ++qg)
#pragma unroll
                    for (int kg2 = 0; kg2 < 2; ++kg2) {
                        const int kg = hh * 2 + kg2;
                        uint2 u;
                        u.x = pack2(c[qg][kg][0], c[qg][kg][1]);
                        u.y = pack2(c[qg][kg][2], c[qg][kg][3]);
                        *(uint2*)&pw[(qg * 16 + lr) * PP + kg2 * 16 + lg * 4] = u;
                    }
                bf16x8 bv[4];
#pragma unroll
                for (int dg = 0; dg < 4; ++dg)
                    bv[dg] = *(const bf16x8*)&vT[(dg * 16 + lr) * VP + kt4 * 64 + hh * 32 + lg * 8];
#pragma unroll
                for (int qg = 0; qg < 2; ++qg) {
                    const bf16x8 ap = *(const bf16x8*)&pw[(qg * 16 + lr) * PP + lg * 8];
#pragma unroll
                    for (int dg = 0; dg < 4; ++dg)
                        acc[qg][dg] = __builtin_amdgcn_mfma_f32_16x16x32_bf16(ap, bv[dg], acc[qg][dg], 0, 0, 0);
                }
            }
        }
    }

    // ---- epilogue: out = acc / l, scattered to original query order ----
#pragma unroll
    for (int qg = 0; qg < 2; ++qg)
#pragma unroll
        for (int r = 0; r < 4; ++r) {
            const float lq = __shfl(l_run[qg], lg * 4 + r);
            const int   qr = __shfl(qrow[qg], lg * 4 + r);
            const float inv = 1.f / lq;
            const int obase = ((b * S + qr) * H + h) << 6;
#pragma unroll
            for (int dg = 0; dg < 4; ++dg)
                out[obase + dg * 16 + lr] = acc[qg][dg][r] * inv;
        }
}

// ---------------------------------------------------------------------------
extern "C" void kernel_launch(void* const* d_in, const int* in_sizes, int n_in,
                              void* d_out, int out_size, void* d_ws, size_t ws_size,
                              hipStream_t stream) {
    const float* q   = (const float*)d_in[0];
    const float* k   = (const float*)d_in[1];
    const float* v   = (const float*)d_in[2];
    const float* pd  = (const float*)d_in[3];
    const int*  sidx = (const int*)d_in[4];
    float* out = (float*)d_out;

    int* hq = (int*)d_ws;
    int* hk = hq + BHS;
    int* qs = hk + BHS;
    int* ks = qs + BHS;
    unsigned short* kbf = (unsigned short*)(ks + BHS);
    unsigned short* vbf = kbf + BSHD;

    k_prep<<<(B * S * H) / 256, 256, 0, stream>>>(q, k, v, pd, hq, hk, kbf, vbf);
    k_sort<<<2 * BH, SORT_NT, 0, stream>>>(hq, hk, qs, ks);
    k_attn<<<BH * NB, 512, 0, stream>>>(q, kbf, vbf, qs, ks, sidx, out);
}